// Round 6
// baseline (25.529 us; speedup 1.0000x reference)
//
#include <hip/hip_runtime.h>

// SNNMaxPool2d winner-take-all forward, 64B sparse probes, 4 windows/wave.
// x: [B=4, C=32, H=64, W=64, T=100] f32 spikes. out: [4,32,32,32,100] one-hot
// of earliest spiking t per 2x2/stride-2 window.
//
// One wave64 handles FOUR windows (16 lanes each). Per window: 4 cells x 4
// lanes x float4 = each cell probed with the 64B-aligned block containing its
// t=0 (requested reads: 256B/window vs 512B in R5 -- L3 serves replays, so
// requested bytes, not HBM granules, set the pace per R5 timing evidence).
// Guaranteed coverage cover1 = 16 - max(align) in {4,12}; tier-2 (+64B/cell,
// ~10% of windows) extends by 16 steps; tier-3 dense scan ~2e-4/window.

#define T_DIM 100

__global__ __launch_bounds__(256) void snn_wta_kernel(
    const float* __restrict__ x, float* __restrict__ out, int n_pix)
{
    const int T = T_DIM;
    const int C = 32, H = 64, W = 64, OH = 32, OW = 32;

    const int wave = threadIdx.x >> 6;   // 0..3
    const int lane = threadIdx.x & 63;
    const int win  = lane >> 4;          // which of 4 windows
    const int q4   = lane & 15;          // lane within window
    const int cell = q4 >> 2;            // 0..3 window cell
    const int q    = q4 & 3;             // lane within cell (4 x float4 = 64B)

    const int p = (blockIdx.x * 4 + wave) * 4 + win;
    if (p >= n_pix) return;              // grid exact; safety

    const int ow = p & (OW - 1);
    int tmp = p >> 5;
    const int oh = tmp & (OH - 1);
    tmp >>= 5;
    const int c = tmp & (C - 1);
    const int b = tmp >> 5;

    const size_t base0 = ((((size_t)b * C + c) * H + oh * 2) * W + ow * 2) * T;
    const float* __restrict__ r0 = x + base0;          // (h,w) then (h,w+1)
    const float* __restrict__ A  = r0
        + ((cell & 2) ? (size_t)W * T : 0)
        + ((cell & 1) ? T : 0);

    // tier-1 probe: the 64B-aligned block containing this cell's t=0
    const float* __restrict__ Ad =
        (const float*)((uintptr_t)A & ~(uintptr_t)63);
    const int moff = (int)(((uintptr_t)A & 63) >> 2);    // junk floats before t=0 (0..15)
    const float4 v = *(const float4*)(Ad + q * 4);
    const int t0 = q * 4 - moff;                         // in [-15, 15]

    int lmint = T;
    if (t0 + 0 >= 0 && v.x > 0.0f) lmint = min(lmint, t0 + 0);
    if (t0 + 1 >= 0 && v.y > 0.0f) lmint = min(lmint, t0 + 1);
    if (t0 + 2 >= 0 && v.z > 0.0f) lmint = min(lmint, t0 + 2);
    if (t0 + 3 >= 0 && v.w > 0.0f) lmint = min(lmint, t0 + 3);

    // 16-lane min-reduce (xor offsets <16 stay within the window's lanes)
    #pragma unroll
    for (int off = 8; off >= 1; off >>= 1)
        lmint = min(lmint, __shfl_xor(lmint, off, 64));

    // guaranteed-covered prefix across all 4 cells:
    // cells 0,2 share alignment (W*T*4 = 25600B % 64 == 0); cells 1,3 share
    const int m0 = (int)(((uintptr_t)r0 & 63) >> 2);
    const int m1 = (int)(((uintptr_t)(r0 + T) & 63) >> 2);
    const int cover1 = 16 - max(m0, m1);

    bool need = (lmint >= cover1);              // window-uniform
    if (__any(need)) {                          // wave-uniform entry
        if (need) {
            // tier-2: next 64B block, covers t in [cover1, cover1+16)
            const float4 u = *(const float4*)(Ad + 16 + q * 4);
            const int t1 = t0 + 16;             // >= 1 always
            if (u.x > 0.0f) lmint = min(lmint, t1 + 0);
            if (u.y > 0.0f) lmint = min(lmint, t1 + 1);
            if (u.z > 0.0f) lmint = min(lmint, t1 + 2);
            if (u.w > 0.0f) lmint = min(lmint, t1 + 3);
        }
        #pragma unroll
        for (int off = 8; off >= 1; off >>= 1)
            lmint = min(lmint, __shfl_xor(lmint, off, 64));

        if (lmint >= cover1 + 16) {             // window-uniform, ~2e-4
            // tier-3 dense scan: 4 lanes per cell, stride 4
            int fb = T;
            for (int t = q; t < T; t += 4) {
                if (A[t] > 0.0f) { fb = t; break; }
            }
            lmint = fb;
            #pragma unroll
            for (int off = 8; off >= 1; off >>= 1)
                lmint = min(lmint, __shfl_xor(lmint, off, 64));
        }
    }

    // write one-hot: 25 float4 per window; lane q4 covers float4 idx q4 and q4+16
    float* __restrict__ o = out + (size_t)p * T;
    {
        const int tw = q4 * 4;
        float4 w4;
        w4.x = (tw     == lmint) ? 1.0f : 0.0f;
        w4.y = (tw + 1 == lmint) ? 1.0f : 0.0f;
        w4.z = (tw + 2 == lmint) ? 1.0f : 0.0f;
        w4.w = (tw + 3 == lmint) ? 1.0f : 0.0f;
        *reinterpret_cast<float4*>(o + tw) = w4;
    }
    if (q4 < 9) {
        const int tw = (q4 + 16) * 4;
        float4 w4;
        w4.x = (tw     == lmint) ? 1.0f : 0.0f;
        w4.y = (tw + 1 == lmint) ? 1.0f : 0.0f;
        w4.z = (tw + 2 == lmint) ? 1.0f : 0.0f;
        w4.w = (tw + 3 == lmint) ? 1.0f : 0.0f;
        *reinterpret_cast<float4*>(o + tw) = w4;
    }
}

extern "C" void kernel_launch(void* const* d_in, const int* in_sizes, int n_in,
                              void* d_out, int out_size, void* d_ws, size_t ws_size,
                              hipStream_t stream) {
    const float* x = (const float*)d_in[0];
    float* out = (float*)d_out;

    const int B = 4, C = 32, OH = 32, OW = 32;
    const int n_pix = B * C * OH * OW;          // 131072
    const int blocks = n_pix / 16;              // 4 windows/wave, 4 waves/block

    snn_wta_kernel<<<blocks, 256, 0, stream>>>(x, out, n_pix);
}

// Round 8
// 22.680 us; speedup vs baseline: 1.1256x; 1.1256x over previous
//
#include <hip/hip_runtime.h>

// SNNMaxPool2d winner-take-all forward — lean line-aligned sparse probe.
// x: [B=4, C=32, H=64, W=64, T=100] f32 spikes. out: [4,32,32,32,100] one-hot
// of earliest spiking t per 2x2/stride-2 window.
//
// R5 structure (best measured: 22.1 us): one wave64 = TWO windows (half-wave
// each); per window 4 cells x 8 lanes x float4 = the 128B-aligned line
// containing each cell's t=0. 4 lines/window is the line-granule read floor
// (cells are 400B apart, never share lines). Tier-2 (+1 line/cell) on ~1.7%
// of waves; dense scan ~1e-6. Trims per-wave VALU: rows are 400B-aligned so
// moff % 4 == 0 -> validity is a single t0>=0 test; candidate via
// cmp-nibble + ctz; m1 = (m0+4)&31 arithmetically; no bounds check (grid
// exact); nontemporal one-hot stores (output never re-read) via native
// clang vector type (HIP float4 class is rejected by the builtin).

#define T_DIM 100

typedef float vfloat4 __attribute__((ext_vector_type(4)));

__global__ __launch_bounds__(256) void snn_wta_kernel(
    const float* __restrict__ x, float* __restrict__ out)
{
    const int T = T_DIM;
    const int W = 64;

    const int wave = threadIdx.x >> 6;   // 0..3
    const int lane = threadIdx.x & 63;
    const int half = lane >> 5;          // which window of the pair
    const int q2   = lane & 31;          // lane within half
    const int cell = q2 >> 3;            // 0..3 window cell
    const int q    = q2 & 7;             // lane within cell (8 x float4 = 128B)

    const int p = (blockIdx.x * 4 + wave) * 2 + half;   // grid exact

    // input offset: (b*32+c) = p>>10, oh = (p>>5)&31, ow = p&31
    const size_t base0 = (size_t)(p >> 10) * 409600
                       + (size_t)((p >> 5) & 31) * 12800
                       + (size_t)(p & 31) * 200;
    const float* __restrict__ r0 = x + base0;          // (h,w) then (h,w+1)
    const float* __restrict__ A  = r0
        + ((cell & 2) ? (size_t)W * T : 0)
        + ((cell & 1) ? T : 0);

    // tier-1 probe: whole 128B line containing this cell's t=0
    const float* __restrict__ Ad =
        (const float*)((uintptr_t)A & ~(uintptr_t)127);
    const int moff = (int)(((uintptr_t)A & 127) >> 2);   // multiple of 4
    const vfloat4 v = *(const vfloat4*)(Ad + q * 4);
    const int t0 = q * 4 - moff;         // multiple of 4; <0 -> whole lane junk

    int nib = (v.x > 0.0f ? 1 : 0) | (v.y > 0.0f ? 2 : 0)
            | (v.z > 0.0f ? 4 : 0) | (v.w > 0.0f ? 8 : 0);
    int lmint = (t0 >= 0 && nib) ? (t0 + __builtin_ctz(nib)) : T;

    // half-wave (32-lane) min-reduce: xor offsets <32 stay within the half
    #pragma unroll
    for (int off = 16; off >= 1; off >>= 1)
        lmint = min(lmint, __shfl_xor(lmint, off, 64));

    // guaranteed-covered prefix: cells 0,2 aligned m0; cells 1,3: (m0+100)%32
    const int m0 = (int)(((uintptr_t)r0 & 127) >> 2);
    const int m1 = (m0 + 4) & 31;
    const int cover1 = 32 - max(m0, m1);

    const bool need = (lmint >= cover1);        // half-uniform
    if (__any(need)) {                          // wave-uniform entry, ~1.7%
        if (need) {
            // tier-2: next 128B line, extends coverage by 32 steps
            const vfloat4 u = *(const vfloat4*)(Ad + 32 + q * 4);
            int nib2 = (u.x > 0.0f ? 1 : 0) | (u.y > 0.0f ? 2 : 0)
                     | (u.z > 0.0f ? 4 : 0) | (u.w > 0.0f ? 8 : 0);
            if (nib2) lmint = min(lmint, t0 + 32 + __builtin_ctz(nib2));
        }
        #pragma unroll
        for (int off = 16; off >= 1; off >>= 1)
            lmint = min(lmint, __shfl_xor(lmint, off, 64));

        if (lmint >= cover1 + 32) {             // ~1e-6: dense scan
            int fb = T;
            for (int t = q; t < T; t += 8) {
                if (A[t] > 0.0f) { fb = t; break; }
            }
            lmint = fb;
            #pragma unroll
            for (int off = 16; off >= 1; off >>= 1)
                lmint = min(lmint, __shfl_xor(lmint, off, 64));
        }
    }

    // one-hot write: 25 float4 per window, contiguous 400B; nontemporal
    float* __restrict__ o = out + (size_t)p * T;
    if (q2 < 25) {
        const int tw = q2 * 4;
        vfloat4 w4;
        w4.x = (tw     == lmint) ? 1.0f : 0.0f;
        w4.y = (tw + 1 == lmint) ? 1.0f : 0.0f;
        w4.z = (tw + 2 == lmint) ? 1.0f : 0.0f;
        w4.w = (tw + 3 == lmint) ? 1.0f : 0.0f;
        __builtin_nontemporal_store(w4, reinterpret_cast<vfloat4*>(o + tw));
    }
}

extern "C" void kernel_launch(void* const* d_in, const int* in_sizes, int n_in,
                              void* d_out, int out_size, void* d_ws, size_t ws_size,
                              hipStream_t stream) {
    const float* x = (const float*)d_in[0];
    float* out = (float*)d_out;

    const int n_pix = 4 * 32 * 32 * 32;         // 131072
    const int blocks = n_pix / 8;               // 2 windows/wave, 4 waves/block

    snn_wta_kernel<<<blocks, 256, 0, stream>>>(x, out);
}